// Round 1
// baseline (307.789 us; speedup 1.0000x reference)
//
#include <hip/hip_runtime.h>
#include <hip/hip_bf16.h>
#include <math.h>

// ---------------------------------------------------------------------------
// EncoderBlock, round 15: algebraic attention collapse.
//  No softmax in the reference => attention is LINEAR:
//    out = 0.125*Q*(K_masked^T V) - 1e9*corr
//  and folds through wo:
//    x1 = x + Q*W'_b + cbo_b,  W'_b = (0.125*M_blkdiag(b))*wo,
//    cbo_b = bo - 1e9*(corr_b @ wo)
//  Replaces attn_masksum (40.6us) + attn_combine with kv_moment (~2.5us) +
//  wprime (~1.5us); wo-proj becomes the batched Q*W' GEMM (same shape/cost).
//  QKV gemm now writes Q row-major and K,V transposed (kvT).
//  Everything else identical to round 14.
// ---------------------------------------------------------------------------

#define EPS 1e-5f

typedef __attribute__((ext_vector_type(8))) short bf16x8;
typedef __attribute__((ext_vector_type(4))) float f32x4;
typedef __attribute__((ext_vector_type(8))) int i32x8;
typedef __attribute__((ext_vector_type(4))) int i32x4;

typedef const __attribute__((address_space(1))) unsigned char glob_byte;
typedef __attribute__((address_space(3))) unsigned char lds_byte;

__device__ __forceinline__ void g2l16(const void* g, void* l) {
  __builtin_amdgcn_global_load_lds((glob_byte*)g, (lds_byte*)l, 16, 0, 0);
}

__device__ __forceinline__ unsigned short f2bf(float f) {
  union { float f; unsigned int u; } v; v.f = f;
  return (unsigned short)((v.u + 0x7FFFu + ((v.u >> 16) & 1u)) >> 16);
}
__device__ __forceinline__ float bf2f(unsigned short b) {
  union { unsigned int u; float f; } v; v.u = (unsigned int)b << 16;
  return v.f;
}
__device__ __forceinline__ unsigned int pk_fp8x4(float a, float b, float c, float d) {
  unsigned int p = 0;
  p = __builtin_amdgcn_cvt_pk_fp8_f32(a, b, p, false);
  p = __builtin_amdgcn_cvt_pk_fp8_f32(c, d, p, true);
  return p;
}

// ---- weights: wq..wo -> bf16 [N][K]; w1/w2 -> fp8 [N][K]; qkv bias; LN1.
__global__ __launch_bounds__(256) void wconv_ln_kernel(
    const float* __restrict__ wq, const float* __restrict__ wk,
    const float* __restrict__ wv, const float* __restrict__ wo,
    const float* __restrict__ w1, const float* __restrict__ w2,
    const float* __restrict__ bq, const float* __restrict__ bk,
    const float* __restrict__ bv,
    unsigned short* __restrict__ wqkvT, unsigned short* __restrict__ woT,
    unsigned char* __restrict__ w1F8, unsigned char* __restrict__ w2F8,
    float* __restrict__ bqkv,
    const float* __restrict__ x, unsigned short* __restrict__ xn,
    const float* __restrict__ ln1a, const float* __restrict__ ln1b) {
  __shared__ float tile[64][65];
  const int bid = blockIdx.x;
  const int t = threadIdx.x;
  if (bid >= 3073) {  // ---- LayerNorm1 (torch: ddof=1, /(std+eps))
    const int row = bid - 3073;
    const float4 v = ((const float4*)(x + (size_t)row * 1024))[t];
    float s  = v.x + v.y + v.z + v.w;
    float ss = v.x * v.x + v.y * v.y + v.z * v.z + v.w * v.w;
#pragma unroll
    for (int off = 32; off > 0; off >>= 1) {
      s  += __shfl_down(s, off, 64);
      ss += __shfl_down(ss, off, 64);
    }
    __shared__ float red[8];
    const int lane = t & 63, wv_ = t >> 6;
    if (lane == 0) { red[wv_] = s; red[4 + wv_] = ss; }
    __syncthreads();
    const float S  = red[0] + red[1] + red[2] + red[3];
    const float SS = red[4] + red[5] + red[6] + red[7];
    const float mean = S * (1.0f / 1024.0f);
    float var = (SS - 1024.0f * mean * mean) * (1.0f / 1023.0f);
    var = fmaxf(var, 0.0f);
    const float scl = ln1a[0] / (sqrtf(var) + EPS);
    const float b = ln1b[0];
    ushort4 o;
    o.x = f2bf((v.x - mean) * scl + b);
    o.y = f2bf((v.y - mean) * scl + b);
    o.z = f2bf((v.z - mean) * scl + b);
    o.w = f2bf((v.w - mean) * scl + b);
    ((ushort4*)(xn + (size_t)row * 1024))[t] = o;
    return;
  }
  if (bid == 3072) {
#pragma unroll
    for (int i = 0; i < 12; ++i) {
      const int n = i * 256 + t;
      bqkv[n] = n < 1024 ? bq[n] : (n < 2048 ? bk[n - 1024] : bv[n - 2048]);
    }
    return;
  }
  const float* src; int K, N, tk, tn;
  unsigned short* dst16 = nullptr; unsigned char* dst8 = nullptr;
  if (bid < 1024) {
    const int m = bid >> 8, loc = bid & 255;
    src = m == 0 ? wq : m == 1 ? wk : m == 2 ? wv : wo;
    dst16 = m == 3 ? woT : (wqkvT + (size_t)m * 1024 * 1024);
    K = 1024; N = 1024; tk = loc >> 4; tn = loc & 15;
  } else if (bid < 2048) {
    const int loc = bid - 1024; src = w1; dst8 = w1F8;
    K = 1024; N = 4096; tk = loc >> 6; tn = loc & 63;
  } else {
    const int loc = bid - 2048; src = w2; dst8 = w2F8;
    K = 4096; N = 1024; tk = loc >> 4; tn = loc & 15;
  }
  const int lr = t >> 4, lc = (t & 15) * 4;
#pragma unroll
  for (int i = 0; i < 4; ++i) {
    const float4 v = *(const float4*)(src + (size_t)(tk * 64 + lr + 16 * i) * N + tn * 64 + lc);
    tile[lr + 16 * i][lc + 0] = v.x;
    tile[lr + 16 * i][lc + 1] = v.y;
    tile[lr + 16 * i][lc + 2] = v.z;
    tile[lr + 16 * i][lc + 3] = v.w;
  }
  __syncthreads();
  const int on = t >> 2, ok = (t & 3) * 16;
#pragma unroll
  for (int jj = 0; jj < 4; ++jj) {
    if (dst8) {
      const unsigned int p = pk_fp8x4(tile[ok + 4 * jj + 0][on], tile[ok + 4 * jj + 1][on],
                                      tile[ok + 4 * jj + 2][on], tile[ok + 4 * jj + 3][on]);
      *(unsigned int*)(dst8 + (size_t)(tn * 64 + on) * K + tk * 64 + ok + 4 * jj) = p;
    } else {
      ushort4 o4;
      o4.x = f2bf(tile[ok + 4 * jj + 0][on]);
      o4.y = f2bf(tile[ok + 4 * jj + 1][on]);
      o4.z = f2bf(tile[ok + 4 * jj + 2][on]);
      o4.w = f2bf(tile[ok + 4 * jj + 3][on]);
      *(ushort4*)(dst16 + (size_t)(tn * 64 + on) * K + tk * 64 + ok + 4 * jj) = o4;
    }
  }
}

// ---- bf16 MFMA GEMM, BK=64, TMxTN, z=1.
//  VSN0 != 0: output columns n >= VSN0 are written TRANSPOSED to C1
//             (C1[(n-VSN0)][m], row stride 4096).
//  BATCHB: B operand and bias are per-batch (batch = m0>>10, 1024x1024 each).
template <int TM, int TN, bool OUT_BF16, bool RELU, bool RES, int VSN0,
          bool BATCHB, int RX, int RY>
__global__ __launch_bounds__(256, 4) void mfma_gemm(
    const unsigned short* __restrict__ A, const unsigned short* __restrict__ Bt,
    const float* __restrict__ bias, const float* __restrict__ res,
    void* __restrict__ C0, void* __restrict__ C1,
    int N, int lda, int ldb, int KH) {
  constexpr int WM = 2, WN = 2;
  constexpr int MSPAN = TM / WM, NSPAN = TN / WN;
  constexpr int MI = MSPAN / 16, NJ = NSPAN / 16;
  __shared__ __align__(16) unsigned short As[TM * 64];
  __shared__ __align__(16) unsigned short Bs[TN * 64];
  const int tid = threadIdx.x, lane = tid & 63;
  const int w = tid >> 6;
  const int quad = lane >> 4, col = lane & 15;
  const int wm = w % WM, wn = w / WM;

  int bx = blockIdx.x, by = blockIdx.y;
  {
    const int gx = gridDim.x;
    const int L = bx + gx * by;
    const int r = L & 7, s = L >> 3;
    const int nrx = gx / RX;
    const int rx = r % nrx, ry = r / nrx;
    bx = rx * RX + s % RX;
    by = ry * RY + (s / RX) % RY;
  }
  const int m0 = by * TM, n0 = bx * TN;
  if (BATCHB) {
    const int bb = m0 >> 10;
    Bt += (size_t)bb * 1024 * ldb;
    bias += bb * 1024;
  }

  f32x4 acc[MI][NJ];
  const f32x4 z4 = {0.f, 0.f, 0.f, 0.f};
#pragma unroll
  for (int i = 0; i < MI; ++i)
#pragma unroll
    for (int j = 0; j < NJ; ++j) acc[i][j] = z4;

  for (int k0 = 0; k0 < KH; k0 += 64) {
    __syncthreads();
#pragma unroll
    for (int t = 0; t < TM / 32; ++t) {
      const int s = t * 256 + tid;
      const int r = s >> 3, c = (s & 7) ^ (r & 7);
      g2l16(A + (size_t)(m0 + r) * lda + k0 + c * 8, (void*)(As + s * 8));
    }
#pragma unroll
    for (int t = 0; t < TN / 32; ++t) {
      const int s = t * 256 + tid;
      const int r = s >> 3, c = (s & 7) ^ (r & 7);
      g2l16(Bt + (size_t)(n0 + r) * ldb + k0 + c * 8, (void*)(Bs + s * 8));
    }
    __syncthreads();
#pragma unroll
    for (int h = 0; h < 2; ++h) {
      bf16x8 af[MI], bfr[NJ];
#pragma unroll
      for (int i = 0; i < MI; ++i) {
        const int rr = wm * MSPAN + i * 16 + col;
        af[i] = *(const bf16x8*)(As + rr * 64 + (((h << 2) | quad) ^ (rr & 7)) * 8);
      }
#pragma unroll
      for (int j = 0; j < NJ; ++j) {
        const int rr = wn * NSPAN + j * 16 + col;
        bfr[j] = *(const bf16x8*)(Bs + rr * 64 + (((h << 2) | quad) ^ (rr & 7)) * 8);
      }
#pragma unroll
      for (int i = 0; i < MI; ++i)
#pragma unroll
        for (int j = 0; j < NJ; ++j)
          acc[i][j] = __builtin_amdgcn_mfma_f32_16x16x32_bf16(af[i], bfr[j], acc[i][j], 0, 0, 0);
    }
  }
#pragma unroll
  for (int i = 0; i < MI; ++i) {
    const int mrow = m0 + wm * MSPAN + i * 16 + quad * 4;
#pragma unroll
    for (int j = 0; j < NJ; ++j) {
      const int n = n0 + wn * NSPAN + j * 16 + col;
      const float bn = bias[n];
      if (VSN0 != 0 && n0 >= VSN0) {
        ushort4 o4;
        o4.x = f2bf(acc[i][j][0] + bn);
        o4.y = f2bf(acc[i][j][1] + bn);
        o4.z = f2bf(acc[i][j][2] + bn);
        o4.w = f2bf(acc[i][j][3] + bn);
        *(ushort4*)((unsigned short*)C1 + (size_t)(n - VSN0) * 4096 + mrow) = o4;
        continue;
      }
#pragma unroll
      for (int r = 0; r < 4; ++r) {
        const int m = mrow + r;
        float v = acc[i][j][r] + bn;
        if (RES)  v += res[(size_t)m * N + n];
        if (RELU) v = fmaxf(v, 0.f);
        if (OUT_BF16) ((unsigned short*)C0)[(size_t)m * N + n] = f2bf(v);
        else          ((float*)C0)[(size_t)m * N + n] = v;
      }
    }
  }
}

// ---- MX-fp8 MFMA GEMM, TM=128 x TN, BK=128, z=1.
template <bool FP8OUT, int TN, int RX, int RY>
__global__ __launch_bounds__(256, 4) void mfma_gemm_fp8(
    const unsigned char* __restrict__ A, const unsigned char* __restrict__ Bt,
    const float* __restrict__ bias, const unsigned short* __restrict__ res16,
    void* __restrict__ C0, int N, int lda, int ldb, int KH) {
  constexpr int NSPAN = TN / 2;
  constexpr int NJ = NSPAN / 16;
  __shared__ __align__(16) unsigned char As[128 * 128];
  __shared__ __align__(16) unsigned char Bs[TN * 128];
  const int tid = threadIdx.x, lane = tid & 63;
  const int w = tid >> 6;
  const int quad = lane >> 4, col = lane & 15;
  const int wm = w & 1, wn = w >> 1;

  int bx = blockIdx.x, by = blockIdx.y;
  {
    const int gx = gridDim.x;
    const int L = bx + gx * by;
    const int r = L & 7, s = L >> 3;
    const int nrx = gx / RX;
    const int rx = r % nrx, ry = r / nrx;
    bx = rx * RX + s % RX;
    by = ry * RY + (s / RX) % RY;
  }
  const int m0 = by * 128, n0 = bx * TN;

  f32x4 acc[4][NJ];
  const f32x4 z4 = {0.f, 0.f, 0.f, 0.f};
#pragma unroll
  for (int i = 0; i < 4; ++i)
#pragma unroll
    for (int j = 0; j < NJ; ++j) acc[i][j] = z4;

  for (int k0 = 0; k0 < KH; k0 += 128) {
    __syncthreads();
#pragma unroll
    for (int t = 0; t < 4; ++t) {
      const int s = t * 256 + tid;
      const int r = s >> 3, c = (s & 7) ^ (r & 7);
      g2l16(A + (size_t)(m0 + r) * lda + k0 + c * 16, (void*)(As + s * 16));
    }
#pragma unroll
    for (int t = 0; t < TN / 32; ++t) {
      const int s = t * 256 + tid;
      const int r = s >> 3, c = (s & 7) ^ (r & 7);
      g2l16(Bt + (size_t)(n0 + r) * ldb + k0 + c * 16, (void*)(Bs + s * 16));
    }
    __syncthreads();
    i32x8 af[4];
#pragma unroll
    for (int i = 0; i < 4; ++i) {
      const int rr = wm * 64 + i * 16 + col;
      const i32x4* rowp = (const i32x4*)(As + rr * 128);
      const i32x4 lo = rowp[(2 * quad) ^ (rr & 7)];
      const i32x4 hi = rowp[(2 * quad + 1) ^ (rr & 7)];
      af[i] = __builtin_shufflevector(lo, hi, 0, 1, 2, 3, 4, 5, 6, 7);
    }
#pragma unroll
    for (int j = 0; j < NJ; ++j) {
      const int rr = wn * NSPAN + j * 16 + col;
      const i32x4* rowp = (const i32x4*)(Bs + rr * 128);
      const i32x4 lo = rowp[(2 * quad) ^ (rr & 7)];
      const i32x4 hi = rowp[(2 * quad + 1) ^ (rr & 7)];
      const i32x8 bfj = __builtin_shufflevector(lo, hi, 0, 1, 2, 3, 4, 5, 6, 7);
#pragma unroll
      for (int i = 0; i < 4; ++i)
        acc[i][j] = __builtin_amdgcn_mfma_scale_f32_16x16x128_f8f6f4(
            af[i], bfj, acc[i][j], 0, 0, 0, 0x7F7F7F7Fu, 0, 0x7F7F7F7Fu);
    }
  }
#pragma unroll
  for (int i = 0; i < 4; ++i) {
    const int mrow = m0 + wm * 64 + i * 16 + quad * 4;
#pragma unroll
    for (int j = 0; j < NJ; ++j) {
      const int n = n0 + wn * NSPAN + j * 16 + col;
      const float bn = bias[n];
#pragma unroll
      for (int r = 0; r < 4; ++r) {
        const int m = mrow + r;
        if (FP8OUT) {
          const float v = fmaxf(acc[i][j][r] + bn, 0.f);
          const unsigned int p = __builtin_amdgcn_cvt_pk_fp8_f32(v, v, 0, false);
          ((unsigned char*)C0)[(size_t)m * N + n] = (unsigned char)(p & 0xFF);
        } else {
          const float v = acc[i][j][r] + bn + bf2f(res16[(size_t)m * N + n]);
          ((float*)C0)[(size_t)m * N + n] = v;
        }
      }
    }
  }
}

// ---- LN2: x1 bf16 -> xn2 fp8 (torch semantics).
__global__ __launch_bounds__(256) void ln2_kernel(
    const unsigned short* __restrict__ x1,
    const float* __restrict__ alpha, const float* __restrict__ beta,
    unsigned char* __restrict__ xn2f8) {
  const int row = blockIdx.x, t = threadIdx.x;
  const size_t i = (size_t)row * 256 + t;
  const ushort4 a4 = ((const ushort4*)x1)[i];
  float4 v;
  v.x = bf2f(a4.x); v.y = bf2f(a4.y); v.z = bf2f(a4.z); v.w = bf2f(a4.w);
  float s  = v.x + v.y + v.z + v.w;
  float ss = v.x * v.x + v.y * v.y + v.z * v.z + v.w * v.w;
#pragma unroll
  for (int off = 32; off > 0; off >>= 1) {
    s  += __shfl_down(s, off, 64);
    ss += __shfl_down(ss, off, 64);
  }
  __shared__ float red[8];
  const int lane = t & 63, wv_ = t >> 6;
  if (lane == 0) { red[wv_] = s; red[4 + wv_] = ss; }
  __syncthreads();
  const float S  = red[0] + red[1] + red[2] + red[3];
  const float SS = red[4] + red[5] + red[6] + red[7];
  const float mean = S * (1.0f / 1024.0f);
  float var = (SS - 1024.0f * mean * mean) * (1.0f / 1023.0f);
  var = fmaxf(var, 0.0f);
  const float scl = alpha[0] / (sqrtf(var) + EPS);
  const float bb = beta[0];
  ((unsigned int*)xn2f8)[i] = pk_fp8x4((v.x - mean) * scl + bb,
                                       (v.y - mean) * scl + bb,
                                       (v.z - mean) * scl + bb,
                                       (v.w - mean) * scl + bb);
}

// ---- kv_moment: per (b,h) M' = 0.125 * sum_{t: mask=1} K[t]⊗V[t]  (64x64 bf16)
//      and corr[b][hd] = sum_{t: mask=0} V[t][hd]  (fp32).
//  kvT: rows 0..1023 = K^T [hd][4096 tok], rows 1024..2047 = V^T.
//  grid 64 = b*16+h; 4 waves; wave w owns d1-tile w. No LDS, no barriers.
__global__ __launch_bounds__(256) void kv_moment_kernel(
    const unsigned short* __restrict__ kvT, const int* __restrict__ mask,
    unsigned short* __restrict__ Mb, float* __restrict__ corr) {
  const int tid = threadIdx.x, lane = tid & 63, w = tid >> 6;
  const int quad = lane >> 4, col = lane & 15;
  const int bh = blockIdx.x, b = bh >> 4, h = bh & 15;
  const unsigned short* kT  = kvT + (size_t)(h * 64 + w * 16 + col) * 4096 + b * 1024;
  const unsigned short* vTb = kvT + (size_t)(1024 + h * 64) * 4096 + b * 1024;
  const int* mrow = mask + b * 1024;
  const f32x4 z4 = {0.f, 0.f, 0.f, 0.f};
  f32x4 acc[4] = {z4, z4, z4, z4};
  float cf[4] = {0.f, 0.f, 0.f, 0.f};
#pragma unroll 2
  for (int t0 = 0; t0 < 1024; t0 += 32) {
    const int tok = t0 + quad * 8;
    const int4 ma = *(const int4*)(mrow + tok);
    const int4 mb2 = *(const int4*)(mrow + tok + 4);
    bf16x8 af = *(const bf16x8*)(kT + tok);
    af[0] = ma.x  ? af[0] : (short)0;
    af[1] = ma.y  ? af[1] : (short)0;
    af[2] = ma.z  ? af[2] : (short)0;
    af[3] = ma.w  ? af[3] : (short)0;
    af[4] = mb2.x ? af[4] : (short)0;
    af[5] = mb2.y ? af[5] : (short)0;
    af[6] = mb2.z ? af[6] : (short)0;
    af[7] = mb2.w ? af[7] : (short)0;
#pragma unroll
    for (int c = 0; c < 4; ++c) {
      const bf16x8 vf = *(const bf16x8*)(vTb + (size_t)(c * 16 + col) * 4096 + tok);
      if (w == 0) {
        if (!ma.x)  cf[c] += bf2f((unsigned short)vf[0]);
        if (!ma.y)  cf[c] += bf2f((unsigned short)vf[1]);
        if (!ma.z)  cf[c] += bf2f((unsigned short)vf[2]);
        if (!ma.w)  cf[c] += bf2f((unsigned short)vf[3]);
        if (!mb2.x) cf[c] += bf2f((unsigned short)vf[4]);
        if (!mb2.y) cf[c] += bf2f((unsigned short)vf[5]);
        if (!mb2.z) cf[c] += bf2f((unsigned short)vf[6]);
        if (!mb2.w) cf[c] += bf2f((unsigned short)vf[7]);
      }
      acc[c] = __builtin_amdgcn_mfma_f32_16x16x32_bf16(af, vf, acc[c], 0, 0, 0);
    }
  }
  unsigned short* Mrow = Mb + (size_t)bh * 4096;
#pragma unroll
  for (int c = 0; c < 4; ++c) {
#pragma unroll
    for (int r = 0; r < 4; ++r)
      Mrow[(w * 16 + quad * 4 + r) * 64 + c * 16 + col] = f2bf(0.125f * acc[c][r]);
  }
  if (w == 0) {
#pragma unroll
    for (int c = 0; c < 4; ++c) {
      float s = cf[c];
      s += __shfl_xor(s, 16, 64);
      s += __shfl_xor(s, 32, 64);
      if (quad == 0) corr[b * 1024 + h * 64 + c * 16 + col] = s;
    }
  }
}

// ---- wprime: W'T[b][n][h*64+d1] = sum_d2 woT[n][h*64+d2]*M'_{b,h}[d1][d2]
//      (Bt layout for the batched attention GEMM) and
//      cboW[b][n] = bo[n] - 1e9 * sum_hd corr[b][hd]*woT[n][hd].
//  grid 64 = b*16 + ntile(64 rows); 4 waves; wave w owns n-rows [nt*64+w*16,+16).
__global__ __launch_bounds__(256) void wprime_kernel(
    const unsigned short* __restrict__ Mb, const unsigned short* __restrict__ woT,
    const float* __restrict__ corr, const float* __restrict__ bo,
    unsigned short* __restrict__ Wbt, float* __restrict__ cboW) {
  __shared__ __align__(16) float corrS[1024];
  const int tid = threadIdx.x, lane = tid & 63, w = tid >> 6;
  const int quad = lane >> 4, col = lane & 15;
  const int blk = blockIdx.x, b = blk >> 4, nt = blk & 15;
  ((f32x4*)corrS)[tid] = ((const f32x4*)(corr + b * 1024))[tid >> 6 ? tid : tid];
  __syncthreads();
  const int nbase = nt * 64 + w * 16;
  const f32x4 z4 = {0.f, 0.f, 0.f, 0.f};
  unsigned short* Wb = Wbt + (size_t)b * 1048576;
#pragma unroll 1
  for (int h = 0; h < 16; ++h) {
    const bf16x8 af0 = *(const bf16x8*)(woT + (size_t)(nbase + col) * 1024 + h * 64 + quad * 8);
    const bf16x8 af1 = *(const bf16x8*)(woT + (size_t)(nbase + col) * 1024 + h * 64 + 32 + quad * 8);
    const unsigned short* Mrow = Mb + (size_t)(b * 16 + h) * 4096;
#pragma unroll
    for (int dt = 0; dt < 4; ++dt) {
      const bf16x8 bf0 = *(const bf16x8*)(Mrow + (dt * 16 + col) * 64 + quad * 8);
      const bf16x8 bf1 = *(const bf16x8*)(Mrow + (dt * 16 + col) * 64 + 32 + quad * 8);
      f32x4 a = __builtin_amdgcn_mfma_f32_16x16x32_bf16(af0, bf0, z4, 0, 0, 0);
      a = __builtin_amdgcn_mfma_f32_16x16x32_bf16(af1, bf1, a, 0, 0, 0);
#pragma unroll
      for (int r = 0; r < 4; ++r)
        Wb[(size_t)(nbase + quad * 4 + r) * 1024 + h * 64 + dt * 16 + col] = f2bf(a[r]);
    }
  }
  // cbo: 4 threads per n-row
  const int rr = tid >> 2, q = tid & 3;
  const int n = nt * 64 + rr;
  float s = 0.f;
  const unsigned short* wrow = woT + (size_t)n * 1024;
#pragma unroll 4
  for (int k = q * 256; k < q * 256 + 256; k += 4) {
    const ushort4 w4 = *(const ushort4*)(wrow + k);
    s += bf2f(w4.x) * corrS[k] + bf2f(w4.y) * corrS[k + 1] +
         bf2f(w4.z) * corrS[k + 2] + bf2f(w4.w) * corrS[k + 3];
  }
  s += __shfl_xor(s, 1, 64);
  s += __shfl_xor(s, 2, 64);
  if (q == 0) cboW[b * 1024 + n] = bo[n] - 1e9f * s;
}

extern "C" void kernel_launch(void* const* d_in, const int* in_sizes, int n_in,
                              void* d_out, int out_size, void* d_ws, size_t ws_size,
                              hipStream_t stream) {
  const float* x    = (const float*)d_in[0];
  const int*   mask = (const int*)d_in[1];
  const float* wq = (const float*)d_in[2];
  const float* bq = (const float*)d_in[3];
  const float* wk = (const float*)d_in[4];
  const float* bk = (const float*)d_in[5];
  const float* wv = (const float*)d_in[6];
  const float* bv = (const float*)d_in[7];
  const float* wo = (const float*)d_in[8];
  const float* bo = (const float*)d_in[9];
  const float* w1 = (const float*)d_in[10];
  const float* b1 = (const float*)d_in[11];
  const float* w2 = (const float*)d_in[12];
  const float* b2 = (const float*)d_in[13];
  const float* ln1a = (const float*)d_in[14];
  const float* ln1b = (const float*)d_in[15];
  const float* ln2a = (const float*)d_in[16];
  const float* ln2b = (const float*)d_in[17];
  float* out = (float*)d_out;
  char* W = (char*)d_ws;
  const size_t MB = 1u << 20;

  unsigned short* wqkvT = (unsigned short*)(W + 0 * MB);   // 6 MB [3072][1024]
  unsigned short* woT   = (unsigned short*)(W + 6 * MB);   // 2 MB
  unsigned char*  w1F8  = (unsigned char*)(W + 8 * MB);    // 4 MB [4096][1024]
  unsigned char*  w2F8  = (unsigned char*)(W + 16 * MB);   // 4 MB [1024][4096]
  float*          bqkv  = (float*)(W + 24 * MB);           // 12 KB
  float*          corr  = (float*)(W + 24 * MB + 65536);   // 16 KB [4][1024]
  float*          cboW  = (float*)(W + 24 * MB + 131072);  // 16 KB [4][1024]
  unsigned short* Mb    = (unsigned short*)(W + 24 * MB + 262144); // 512 KB [64][64][64]
  unsigned short* xn    = (unsigned short*)(W + 25 * MB);  // 8 MB bf16
  unsigned char*  xn2f8 = (unsigned char*)(W + 25 * MB);   // 4 MB (xn dead)
  unsigned short* qRM   = (unsigned short*)(W + 33 * MB);  // 8 MB Q [4096][1024]
  unsigned short* kvT   = (unsigned short*)(W + 41 * MB);  // 16 MB [2048][4096]
  unsigned short* Wbt   = (unsigned short*)(W + 57 * MB);  // 8 MB [4][1024][1024]
  unsigned short* x1    = (unsigned short*)(W + 65 * MB);  // 8 MB bf16
  unsigned char*  hbF8  = (unsigned char*)(W + 41 * MB);   // 16 MB (kvT dead)

  // weights + qkv bias + LN1 in one launch
  wconv_ln_kernel<<<7169, 256, 0, stream>>>(wq, wk, wv, wo, w1, w2, bq, bk, bv,
                                            wqkvT, woT, w1F8, w2F8, bqkv,
                                            x, xn, ln1a, ln1b);
  // fused q|k|v GEMM (bf16): Q row-major -> qRM, K and V transposed -> kvT.
  mfma_gemm<128, 128, true, false, false, 1024, false, 12, 8>
      <<<dim3(24, 32), 256, 0, stream>>>(
      xn, wqkvT, bqkv, nullptr, qRM, kvT, 1024, 1024, 1024, 1024);
  // per-(b,h) masked moment M' (bf16, 0.125-scaled) + corr
  kv_moment_kernel<<<64, 256, 0, stream>>>(kvT, mask, Mb, corr);
  // W'_b = M'_blkdiag * wo (Bt layout) + per-batch bias cbo
  wprime_kernel<<<64, 256, 0, stream>>>(Mb, woT, corr, bo, Wbt, cboW);
  // batched attention+wo GEMM: x1 = x + Q*W'_b + cbo_b  (bf16)
  mfma_gemm<128, 64, true, false, true, 0, true, 8, 8>
      <<<dim3(16, 32), 256, 0, stream>>>(
      qRM, Wbt, cboW, x, x1, nullptr, 1024, 1024, 1024, 1024);
  // LN2: x1 -> xn2 fp8
  ln2_kernel<<<4096, 256, 0, stream>>>(x1, ln2a, ln2b, xn2f8);
  // FFN1 fp8: 1024 blocks, BK=128, relu -> fp8 hb
  mfma_gemm_fp8<true, 128, 16, 8><<<dim3(32, 32), 256, 0, stream>>>(
      xn2f8, w1F8, b1, nullptr, hbF8, 4096, 1024, 1024, 1024);
  // FFN2 fp8 z=1, TM128xTN64 (512 blocks), K=4096; epilogue: +b2 +x1 -> out
  mfma_gemm_fp8<false, 64, 8, 8><<<dim3(16, 32), 256, 0, stream>>>(
      hbF8, w2F8, b2, x1, out, 1024, 4096, 4096, 4096);
}

// Round 2
// 276.954 us; speedup vs baseline: 1.1113x; 1.1113x over previous
//
#include <hip/hip_runtime.h>
#include <hip/hip_bf16.h>
#include <math.h>

// ---------------------------------------------------------------------------
// EncoderBlock, round 16: fused moment+wprime.
//  Round-15 analysis: kv_moment was 64 blocks with 4x-redundant per-lane V
//  gathers (~40MB, latency-bound) and wprime was a separate dispatch. Fused
//  into one 512-thread kernel: LDS-staged K/V tiles (4 big stages, V read
//  once), M + corr live in LDS, wprime phase after one barrier, cbo via
//  atomicAdd into bo-initialized cboW. -1 dispatch, -Mb/-corr globals.
//  Everything else identical to round 15.
// ---------------------------------------------------------------------------

#define EPS 1e-5f

typedef __attribute__((ext_vector_type(8))) short bf16x8;
typedef __attribute__((ext_vector_type(4))) float f32x4;
typedef __attribute__((ext_vector_type(8))) int i32x8;
typedef __attribute__((ext_vector_type(4))) int i32x4;

typedef const __attribute__((address_space(1))) unsigned char glob_byte;
typedef __attribute__((address_space(3))) unsigned char lds_byte;

__device__ __forceinline__ void g2l16(const void* g, void* l) {
  __builtin_amdgcn_global_load_lds((glob_byte*)g, (lds_byte*)l, 16, 0, 0);
}

__device__ __forceinline__ unsigned short f2bf(float f) {
  union { float f; unsigned int u; } v; v.f = f;
  return (unsigned short)((v.u + 0x7FFFu + ((v.u >> 16) & 1u)) >> 16);
}
__device__ __forceinline__ float bf2f(unsigned short b) {
  union { unsigned int u; float f; } v; v.u = (unsigned int)b << 16;
  return v.f;
}
__device__ __forceinline__ unsigned int pk_fp8x4(float a, float b, float c, float d) {
  unsigned int p = 0;
  p = __builtin_amdgcn_cvt_pk_fp8_f32(a, b, p, false);
  p = __builtin_amdgcn_cvt_pk_fp8_f32(c, d, p, true);
  return p;
}

// ---- weights: wq..wo -> bf16 [N][K]; w1/w2 -> fp8 [N][K]; qkv bias; LN1;
//      cboW init to bo (per batch).
__global__ __launch_bounds__(256) void wconv_ln_kernel(
    const float* __restrict__ wq, const float* __restrict__ wk,
    const float* __restrict__ wv, const float* __restrict__ wo,
    const float* __restrict__ w1, const float* __restrict__ w2,
    const float* __restrict__ bq, const float* __restrict__ bk,
    const float* __restrict__ bv, const float* __restrict__ bo,
    unsigned short* __restrict__ wqkvT, unsigned short* __restrict__ woT,
    unsigned char* __restrict__ w1F8, unsigned char* __restrict__ w2F8,
    float* __restrict__ bqkv, float* __restrict__ cboW,
    const float* __restrict__ x, unsigned short* __restrict__ xn,
    const float* __restrict__ ln1a, const float* __restrict__ ln1b) {
  __shared__ float tile[64][65];
  const int bid = blockIdx.x;
  const int t = threadIdx.x;
  if (bid >= 3073) {  // ---- LayerNorm1 (torch: ddof=1, /(std+eps))
    const int row = bid - 3073;
    const float4 v = ((const float4*)(x + (size_t)row * 1024))[t];
    float s  = v.x + v.y + v.z + v.w;
    float ss = v.x * v.x + v.y * v.y + v.z * v.z + v.w * v.w;
#pragma unroll
    for (int off = 32; off > 0; off >>= 1) {
      s  += __shfl_down(s, off, 64);
      ss += __shfl_down(ss, off, 64);
    }
    __shared__ float red[8];
    const int lane = t & 63, wv_ = t >> 6;
    if (lane == 0) { red[wv_] = s; red[4 + wv_] = ss; }
    __syncthreads();
    const float S  = red[0] + red[1] + red[2] + red[3];
    const float SS = red[4] + red[5] + red[6] + red[7];
    const float mean = S * (1.0f / 1024.0f);
    float var = (SS - 1024.0f * mean * mean) * (1.0f / 1023.0f);
    var = fmaxf(var, 0.0f);
    const float scl = ln1a[0] / (sqrtf(var) + EPS);
    const float b = ln1b[0];
    ushort4 o;
    o.x = f2bf((v.x - mean) * scl + b);
    o.y = f2bf((v.y - mean) * scl + b);
    o.z = f2bf((v.z - mean) * scl + b);
    o.w = f2bf((v.w - mean) * scl + b);
    ((ushort4*)(xn + (size_t)row * 1024))[t] = o;
    return;
  }
  if (bid == 3072) {
#pragma unroll
    for (int i = 0; i < 12; ++i) {
      const int n = i * 256 + t;
      bqkv[n] = n < 1024 ? bq[n] : (n < 2048 ? bk[n - 1024] : bv[n - 2048]);
    }
#pragma unroll
    for (int i = 0; i < 16; ++i) {
      const int idx = i * 256 + t;
      cboW[idx] = bo[idx & 1023];
    }
    return;
  }
  const float* src; int K, N, tk, tn;
  unsigned short* dst16 = nullptr; unsigned char* dst8 = nullptr;
  if (bid < 1024) {
    const int m = bid >> 8, loc = bid & 255;
    src = m == 0 ? wq : m == 1 ? wk : m == 2 ? wv : wo;
    dst16 = m == 3 ? woT : (wqkvT + (size_t)m * 1024 * 1024);
    K = 1024; N = 1024; tk = loc >> 4; tn = loc & 15;
  } else if (bid < 2048) {
    const int loc = bid - 1024; src = w1; dst8 = w1F8;
    K = 1024; N = 4096; tk = loc >> 6; tn = loc & 63;
  } else {
    const int loc = bid - 2048; src = w2; dst8 = w2F8;
    K = 4096; N = 1024; tk = loc >> 4; tn = loc & 15;
  }
  const int lr = t >> 4, lc = (t & 15) * 4;
#pragma unroll
  for (int i = 0; i < 4; ++i) {
    const float4 v = *(const float4*)(src + (size_t)(tk * 64 + lr + 16 * i) * N + tn * 64 + lc);
    tile[lr + 16 * i][lc + 0] = v.x;
    tile[lr + 16 * i][lc + 1] = v.y;
    tile[lr + 16 * i][lc + 2] = v.z;
    tile[lr + 16 * i][lc + 3] = v.w;
  }
  __syncthreads();
  const int on = t >> 2, ok = (t & 3) * 16;
#pragma unroll
  for (int jj = 0; jj < 4; ++jj) {
    if (dst8) {
      const unsigned int p = pk_fp8x4(tile[ok + 4 * jj + 0][on], tile[ok + 4 * jj + 1][on],
                                      tile[ok + 4 * jj + 2][on], tile[ok + 4 * jj + 3][on]);
      *(unsigned int*)(dst8 + (size_t)(tn * 64 + on) * K + tk * 64 + ok + 4 * jj) = p;
    } else {
      ushort4 o4;
      o4.x = f2bf(tile[ok + 4 * jj + 0][on]);
      o4.y = f2bf(tile[ok + 4 * jj + 1][on]);
      o4.z = f2bf(tile[ok + 4 * jj + 2][on]);
      o4.w = f2bf(tile[ok + 4 * jj + 3][on]);
      *(ushort4*)(dst16 + (size_t)(tn * 64 + on) * K + tk * 64 + ok + 4 * jj) = o4;
    }
  }
}

// ---- bf16 MFMA GEMM, BK=64, TMxTN, z=1.
//  VSN0 != 0: output columns n >= VSN0 are written TRANSPOSED to C1
//             (C1[(n-VSN0)][m], row stride 4096).
//  BATCHB: B operand and bias are per-batch (batch = m0>>10, 1024x1024 each).
template <int TM, int TN, bool OUT_BF16, bool RELU, bool RES, int VSN0,
          bool BATCHB, int RX, int RY>
__global__ __launch_bounds__(256, 4) void mfma_gemm(
    const unsigned short* __restrict__ A, const unsigned short* __restrict__ Bt,
    const float* __restrict__ bias, const float* __restrict__ res,
    void* __restrict__ C0, void* __restrict__ C1,
    int N, int lda, int ldb, int KH) {
  constexpr int WM = 2, WN = 2;
  constexpr int MSPAN = TM / WM, NSPAN = TN / WN;
  constexpr int MI = MSPAN / 16, NJ = NSPAN / 16;
  __shared__ __align__(16) unsigned short As[TM * 64];
  __shared__ __align__(16) unsigned short Bs[TN * 64];
  const int tid = threadIdx.x, lane = tid & 63;
  const int w = tid >> 6;
  const int quad = lane >> 4, col = lane & 15;
  const int wm = w % WM, wn = w / WM;

  int bx = blockIdx.x, by = blockIdx.y;
  {
    const int gx = gridDim.x;
    const int L = bx + gx * by;
    const int r = L & 7, s = L >> 3;
    const int nrx = gx / RX;
    const int rx = r % nrx, ry = r / nrx;
    bx = rx * RX + s % RX;
    by = ry * RY + (s / RX) % RY;
  }
  const int m0 = by * TM, n0 = bx * TN;
  if (BATCHB) {
    const int bb = m0 >> 10;
    Bt += (size_t)bb * 1024 * ldb;
    bias += bb * 1024;
  }

  f32x4 acc[MI][NJ];
  const f32x4 z4 = {0.f, 0.f, 0.f, 0.f};
#pragma unroll
  for (int i = 0; i < MI; ++i)
#pragma unroll
    for (int j = 0; j < NJ; ++j) acc[i][j] = z4;

  for (int k0 = 0; k0 < KH; k0 += 64) {
    __syncthreads();
#pragma unroll
    for (int t = 0; t < TM / 32; ++t) {
      const int s = t * 256 + tid;
      const int r = s >> 3, c = (s & 7) ^ (r & 7);
      g2l16(A + (size_t)(m0 + r) * lda + k0 + c * 8, (void*)(As + s * 8));
    }
#pragma unroll
    for (int t = 0; t < TN / 32; ++t) {
      const int s = t * 256 + tid;
      const int r = s >> 3, c = (s & 7) ^ (r & 7);
      g2l16(Bt + (size_t)(n0 + r) * ldb + k0 + c * 8, (void*)(Bs + s * 8));
    }
    __syncthreads();
#pragma unroll
    for (int h = 0; h < 2; ++h) {
      bf16x8 af[MI], bfr[NJ];
#pragma unroll
      for (int i = 0; i < MI; ++i) {
        const int rr = wm * MSPAN + i * 16 + col;
        af[i] = *(const bf16x8*)(As + rr * 64 + (((h << 2) | quad) ^ (rr & 7)) * 8);
      }
#pragma unroll
      for (int j = 0; j < NJ; ++j) {
        const int rr = wn * NSPAN + j * 16 + col;
        bfr[j] = *(const bf16x8*)(Bs + rr * 64 + (((h << 2) | quad) ^ (rr & 7)) * 8);
      }
#pragma unroll
      for (int i = 0; i < MI; ++i)
#pragma unroll
        for (int j = 0; j < NJ; ++j)
          acc[i][j] = __builtin_amdgcn_mfma_f32_16x16x32_bf16(af[i], bfr[j], acc[i][j], 0, 0, 0);
    }
  }
#pragma unroll
  for (int i = 0; i < MI; ++i) {
    const int mrow = m0 + wm * MSPAN + i * 16 + quad * 4;
#pragma unroll
    for (int j = 0; j < NJ; ++j) {
      const int n = n0 + wn * NSPAN + j * 16 + col;
      const float bn = bias[n];
      if (VSN0 != 0 && n0 >= VSN0) {
        ushort4 o4;
        o4.x = f2bf(acc[i][j][0] + bn);
        o4.y = f2bf(acc[i][j][1] + bn);
        o4.z = f2bf(acc[i][j][2] + bn);
        o4.w = f2bf(acc[i][j][3] + bn);
        *(ushort4*)((unsigned short*)C1 + (size_t)(n - VSN0) * 4096 + mrow) = o4;
        continue;
      }
#pragma unroll
      for (int r = 0; r < 4; ++r) {
        const int m = mrow + r;
        float v = acc[i][j][r] + bn;
        if (RES)  v += res[(size_t)m * N + n];
        if (RELU) v = fmaxf(v, 0.f);
        if (OUT_BF16) ((unsigned short*)C0)[(size_t)m * N + n] = f2bf(v);
        else          ((float*)C0)[(size_t)m * N + n] = v;
      }
    }
  }
}

// ---- MX-fp8 MFMA GEMM, TM=128 x TN, BK=128, z=1.
template <bool FP8OUT, int TN, int RX, int RY>
__global__ __launch_bounds__(256, 4) void mfma_gemm_fp8(
    const unsigned char* __restrict__ A, const unsigned char* __restrict__ Bt,
    const float* __restrict__ bias, const unsigned short* __restrict__ res16,
    void* __restrict__ C0, int N, int lda, int ldb, int KH) {
  constexpr int NSPAN = TN / 2;
  constexpr int NJ = NSPAN / 16;
  __shared__ __align__(16) unsigned char As[128 * 128];
  __shared__ __align__(16) unsigned char Bs[TN * 128];
  const int tid = threadIdx.x, lane = tid & 63;
  const int w = tid >> 6;
  const int quad = lane >> 4, col = lane & 15;
  const int wm = w & 1, wn = w >> 1;

  int bx = blockIdx.x, by = blockIdx.y;
  {
    const int gx = gridDim.x;
    const int L = bx + gx * by;
    const int r = L & 7, s = L >> 3;
    const int nrx = gx / RX;
    const int rx = r % nrx, ry = r / nrx;
    bx = rx * RX + s % RX;
    by = ry * RY + (s / RX) % RY;
  }
  const int m0 = by * 128, n0 = bx * TN;

  f32x4 acc[4][NJ];
  const f32x4 z4 = {0.f, 0.f, 0.f, 0.f};
#pragma unroll
  for (int i = 0; i < 4; ++i)
#pragma unroll
    for (int j = 0; j < NJ; ++j) acc[i][j] = z4;

  for (int k0 = 0; k0 < KH; k0 += 128) {
    __syncthreads();
#pragma unroll
    for (int t = 0; t < 4; ++t) {
      const int s = t * 256 + tid;
      const int r = s >> 3, c = (s & 7) ^ (r & 7);
      g2l16(A + (size_t)(m0 + r) * lda + k0 + c * 16, (void*)(As + s * 16));
    }
#pragma unroll
    for (int t = 0; t < TN / 32; ++t) {
      const int s = t * 256 + tid;
      const int r = s >> 3, c = (s & 7) ^ (r & 7);
      g2l16(Bt + (size_t)(n0 + r) * ldb + k0 + c * 16, (void*)(Bs + s * 16));
    }
    __syncthreads();
    i32x8 af[4];
#pragma unroll
    for (int i = 0; i < 4; ++i) {
      const int rr = wm * 64 + i * 16 + col;
      const i32x4* rowp = (const i32x4*)(As + rr * 128);
      const i32x4 lo = rowp[(2 * quad) ^ (rr & 7)];
      const i32x4 hi = rowp[(2 * quad + 1) ^ (rr & 7)];
      af[i] = __builtin_shufflevector(lo, hi, 0, 1, 2, 3, 4, 5, 6, 7);
    }
#pragma unroll
    for (int j = 0; j < NJ; ++j) {
      const int rr = wn * NSPAN + j * 16 + col;
      const i32x4* rowp = (const i32x4*)(Bs + rr * 128);
      const i32x4 lo = rowp[(2 * quad) ^ (rr & 7)];
      const i32x4 hi = rowp[(2 * quad + 1) ^ (rr & 7)];
      const i32x8 bfj = __builtin_shufflevector(lo, hi, 0, 1, 2, 3, 4, 5, 6, 7);
#pragma unroll
      for (int i = 0; i < 4; ++i)
        acc[i][j] = __builtin_amdgcn_mfma_scale_f32_16x16x128_f8f6f4(
            af[i], bfj, acc[i][j], 0, 0, 0, 0x7F7F7F7Fu, 0, 0x7F7F7F7Fu);
    }
  }
#pragma unroll
  for (int i = 0; i < 4; ++i) {
    const int mrow = m0 + wm * 64 + i * 16 + quad * 4;
#pragma unroll
    for (int j = 0; j < NJ; ++j) {
      const int n = n0 + wn * NSPAN + j * 16 + col;
      const float bn = bias[n];
#pragma unroll
      for (int r = 0; r < 4; ++r) {
        const int m = mrow + r;
        if (FP8OUT) {
          const float v = fmaxf(acc[i][j][r] + bn, 0.f);
          const unsigned int p = __builtin_amdgcn_cvt_pk_fp8_f32(v, v, 0, false);
          ((unsigned char*)C0)[(size_t)m * N + n] = (unsigned char)(p & 0xFF);
        } else {
          const float v = acc[i][j][r] + bn + bf2f(res16[(size_t)m * N + n]);
          ((float*)C0)[(size_t)m * N + n] = v;
        }
      }
    }
  }
}

// ---- LN2: x1 bf16 -> xn2 fp8 (torch semantics).
__global__ __launch_bounds__(256) void ln2_kernel(
    const unsigned short* __restrict__ x1,
    const float* __restrict__ alpha, const float* __restrict__ beta,
    unsigned char* __restrict__ xn2f8) {
  const int row = blockIdx.x, t = threadIdx.x;
  const size_t i = (size_t)row * 256 + t;
  const ushort4 a4 = ((const ushort4*)x1)[i];
  float4 v;
  v.x = bf2f(a4.x); v.y = bf2f(a4.y); v.z = bf2f(a4.z); v.w = bf2f(a4.w);
  float s  = v.x + v.y + v.z + v.w;
  float ss = v.x * v.x + v.y * v.y + v.z * v.z + v.w * v.w;
#pragma unroll
  for (int off = 32; off > 0; off >>= 1) {
    s  += __shfl_down(s, off, 64);
    ss += __shfl_down(ss, off, 64);
  }
  __shared__ float red[8];
  const int lane = t & 63, wv_ = t >> 6;
  if (lane == 0) { red[wv_] = s; red[4 + wv_] = ss; }
  __syncthreads();
  const float S  = red[0] + red[1] + red[2] + red[3];
  const float SS = red[4] + red[5] + red[6] + red[7];
  const float mean = S * (1.0f / 1024.0f);
  float var = (SS - 1024.0f * mean * mean) * (1.0f / 1023.0f);
  var = fmaxf(var, 0.0f);
  const float scl = alpha[0] / (sqrtf(var) + EPS);
  const float bb = beta[0];
  ((unsigned int*)xn2f8)[i] = pk_fp8x4((v.x - mean) * scl + bb,
                                       (v.y - mean) * scl + bb,
                                       (v.z - mean) * scl + bb,
                                       (v.w - mean) * scl + bb);
}

// ---- fused moment + wprime: per (b,h)
//  Phase 1: M = 0.125 * sum_{t: mask=1} K[t] (x) V[t]  (64x64, LDS bf16)
//           corrS[d2] = sum_{t: mask=0} V[t][d2]        (LDS fp32)
//    K^T/V^T tiles LDS-staged (4 stages x 256 tokens, V read ONCE).
//    8 waves: w&3 = d1-tile, w>>2 = d2-half.
//  Phase 2: W'T[b][n][h*64+d1] = sum_d2 woT[n][h*64+d2]*M[d1][d2]  (all n)
//           cboW[b][n] += -1e9 * sum_d2 corrS[d2]*woT[n][h*64+d2] (atomic;
//           cboW pre-initialized to bo by wconv_ln).
__global__ __launch_bounds__(512) void moment_kernel(
    const unsigned short* __restrict__ kvT, const int* __restrict__ mask,
    const unsigned short* __restrict__ woT,
    unsigned short* __restrict__ Wbt, float* __restrict__ cboW) {
  __shared__ __align__(16) unsigned short Ks[64 * 256];
  __shared__ __align__(16) unsigned short Vs[64 * 256];
  __shared__ __align__(16) unsigned short Ms[64 * 64];
  __shared__ float corrS[64];
  const int tid = threadIdx.x, lane = tid & 63, w = tid >> 6;
  const int quad = lane >> 4, col = lane & 15;
  const int bh = blockIdx.x, b = bh >> 4, h = bh & 15;
  const int w4 = w & 3, ch = w >> 2;
  const int* mrow = mask + b * 1024;
  const f32x4 z4 = {0.f, 0.f, 0.f, 0.f};
  f32x4 acc[2] = {z4, z4};
  float cf[2] = {0.f, 0.f};
  const size_t kbase = (size_t)(h * 64) * 4096 + b * 1024;
  const size_t vbase = (size_t)(1024 + h * 64) * 4096 + b * 1024;

  for (int st = 0; st < 4; ++st) {
    const int t0 = st * 256;
    __syncthreads();
#pragma unroll
    for (int i = 0; i < 4; ++i) {
      const int s = i * 512 + tid;
      const int r = s >> 5, c = (s & 31) ^ (r & 31);
      g2l16(kvT + kbase + (size_t)r * 4096 + t0 + c * 8, (void*)(Ks + s * 8));
      g2l16(kvT + vbase + (size_t)r * 4096 + t0 + c * 8, (void*)(Vs + s * 8));
    }
    __syncthreads();
#pragma unroll
    for (int ss = 0; ss < 4; ++ss) {
#pragma unroll
      for (int kk = 0; kk < 2; ++kk) {
        const int q = ss * 8 + kk * 4 + quad;
        const int gtok = t0 + q * 8;
        const int4 m0 = *(const int4*)(mrow + gtok);
        const int4 m1 = *(const int4*)(mrow + gtok + 4);
        const int rr = w4 * 16 + col;
        bf16x8 af = *(const bf16x8*)(Ks + rr * 256 + ((q ^ (rr & 31)) * 8));
        af[0] = m0.x ? af[0] : (short)0;
        af[1] = m0.y ? af[1] : (short)0;
        af[2] = m0.z ? af[2] : (short)0;
        af[3] = m0.w ? af[3] : (short)0;
        af[4] = m1.x ? af[4] : (short)0;
        af[5] = m1.y ? af[5] : (short)0;
        af[6] = m1.z ? af[6] : (short)0;
        af[7] = m1.w ? af[7] : (short)0;
#pragma unroll
        for (int cl = 0; cl < 2; ++cl) {
          const int vr = (ch * 2 + cl) * 16 + col;
          const bf16x8 vf = *(const bf16x8*)(Vs + vr * 256 + ((q ^ (vr & 31)) * 8));
          if (w4 == 0) {
            if (!m0.x) cf[cl] += bf2f((unsigned short)vf[0]);
            if (!m0.y) cf[cl] += bf2f((unsigned short)vf[1]);
            if (!m0.z) cf[cl] += bf2f((unsigned short)vf[2]);
            if (!m0.w) cf[cl] += bf2f((unsigned short)vf[3]);
            if (!m1.x) cf[cl] += bf2f((unsigned short)vf[4]);
            if (!m1.y) cf[cl] += bf2f((unsigned short)vf[5]);
            if (!m1.z) cf[cl] += bf2f((unsigned short)vf[6]);
            if (!m1.w) cf[cl] += bf2f((unsigned short)vf[7]);
          }
          acc[cl] = __builtin_amdgcn_mfma_f32_16x16x32_bf16(af, vf, acc[cl], 0, 0, 0);
        }
      }
    }
  }
  // corr: reduce over quads (waves with w4==0 cover all 64 d2-rows)
  if (w4 == 0) {
#pragma unroll
    for (int cl = 0; cl < 2; ++cl) {
      float s = cf[cl];
      s += __shfl_xor(s, 16, 64);
      s += __shfl_xor(s, 32, 64);
      if (quad == 0) corrS[(ch * 2 + cl) * 16 + col] = s;
    }
  }
  // M -> LDS (bf16, 0.125-scaled, chunk-swizzled for phase-2 b128 reads)
#pragma unroll
  for (int cl = 0; cl < 2; ++cl) {
    const int d2 = (ch * 2 + cl) * 16 + col;
#pragma unroll
    for (int r = 0; r < 4; ++r) {
      const int d1 = w4 * 16 + quad * 4 + r;
      Ms[d1 * 64 + ((d2 >> 3) ^ (d1 & 7)) * 8 + (d2 & 7)] = f2bf(0.125f * acc[cl][r]);
    }
  }
  __syncthreads();

  // ---- phase 2: W' for all n (8 n-tiles per wave)
  unsigned short* Wb = Wbt + (size_t)b * 1048576;
#pragma unroll 1
  for (int nt8 = 0; nt8 < 8; ++nt8) {
    const int nbase = (w * 8 + nt8) * 16;
    const bf16x8 af0 = *(const bf16x8*)(woT + (size_t)(nbase + col) * 1024 + h * 64 + quad * 8);
    const bf16x8 af1 = *(const bf16x8*)(woT + (size_t)(nbase + col) * 1024 + h * 64 + 32 + quad * 8);
#pragma unroll
    for (int dt = 0; dt < 4; ++dt) {
      const int d1r = dt * 16 + col;
      const bf16x8 bf0 = *(const bf16x8*)(Ms + d1r * 64 + ((quad ^ (d1r & 7)) * 8));
      const bf16x8 bf1 = *(const bf16x8*)(Ms + d1r * 64 + (((4 + quad) ^ (d1r & 7)) * 8));
      f32x4 a = __builtin_amdgcn_mfma_f32_16x16x32_bf16(af0, bf0, z4, 0, 0, 0);
      a = __builtin_amdgcn_mfma_f32_16x16x32_bf16(af1, bf1, a, 0, 0, 0);
#pragma unroll
      for (int r = 0; r < 4; ++r)
        Wb[(size_t)(nbase + quad * 4 + r) * 1024 + h * 64 + dt * 16 + col] = f2bf(a[r]);
    }
  }
  // ---- cbo contribution for this h (2 n-rows per thread)
#pragma unroll
  for (int rep = 0; rep < 2; ++rep) {
    const int n = rep * 512 + tid;
    const unsigned short* wrow = woT + (size_t)n * 1024 + h * 64;
    float s = 0.f;
#pragma unroll
    for (int k = 0; k < 64; k += 8) {
      const bf16x8 w8 = *(const bf16x8*)(wrow + k);
      s += bf2f((unsigned short)w8[0]) * corrS[k + 0] +
           bf2f((unsigned short)w8[1]) * corrS[k + 1] +
           bf2f((unsigned short)w8[2]) * corrS[k + 2] +
           bf2f((unsigned short)w8[3]) * corrS[k + 3] +
           bf2f((unsigned short)w8[4]) * corrS[k + 4] +
           bf2f((unsigned short)w8[5]) * corrS[k + 5] +
           bf2f((unsigned short)w8[6]) * corrS[k + 6] +
           bf2f((unsigned short)w8[7]) * corrS[k + 7];
    }
    atomicAdd(cboW + b * 1024 + n, -1e9f * s);
  }
}

extern "C" void kernel_launch(void* const* d_in, const int* in_sizes, int n_in,
                              void* d_out, int out_size, void* d_ws, size_t ws_size,
                              hipStream_t stream) {
  const float* x    = (const float*)d_in[0];
  const int*   mask = (const int*)d_in[1];
  const float* wq = (const float*)d_in[2];
  const float* bq = (const float*)d_in[3];
  const float* wk = (const float*)d_in[4];
  const float* bk = (const float*)d_in[5];
  const float* wv = (const float*)d_in[6];
  const float* bv = (const float*)d_in[7];
  const float* wo = (const float*)d_in[8];
  const float* bo = (const float*)d_in[9];
  const float* w1 = (const float*)d_in[10];
  const float* b1 = (const float*)d_in[11];
  const float* w2 = (const float*)d_in[12];
  const float* b2 = (const float*)d_in[13];
  const float* ln1a = (const float*)d_in[14];
  const float* ln1b = (const float*)d_in[15];
  const float* ln2a = (const float*)d_in[16];
  const float* ln2b = (const float*)d_in[17];
  float* out = (float*)d_out;
  char* W = (char*)d_ws;
  const size_t MB = 1u << 20;

  unsigned short* wqkvT = (unsigned short*)(W + 0 * MB);   // 6 MB [3072][1024]
  unsigned short* woT   = (unsigned short*)(W + 6 * MB);   // 2 MB
  unsigned char*  w1F8  = (unsigned char*)(W + 8 * MB);    // 4 MB [4096][1024]
  unsigned char*  w2F8  = (unsigned char*)(W + 16 * MB);   // 4 MB [1024][4096]
  float*          bqkv  = (float*)(W + 24 * MB);           // 12 KB
  float*          cboW  = (float*)(W + 24 * MB + 131072);  // 16 KB [4][1024]
  unsigned short* xn    = (unsigned short*)(W + 25 * MB);  // 8 MB bf16
  unsigned char*  xn2f8 = (unsigned char*)(W + 25 * MB);   // 4 MB (xn dead)
  unsigned short* qRM   = (unsigned short*)(W + 33 * MB);  // 8 MB Q [4096][1024]
  unsigned short* kvT   = (unsigned short*)(W + 41 * MB);  // 16 MB [2048][4096]
  unsigned short* Wbt   = (unsigned short*)(W + 57 * MB);  // 8 MB [4][1024][1024]
  unsigned short* x1    = (unsigned short*)(W + 65 * MB);  // 8 MB bf16
  unsigned char*  hbF8  = (unsigned char*)(W + 41 * MB);   // 16 MB (kvT dead)

  // weights + qkv bias + cbo init + LN1 in one launch
  wconv_ln_kernel<<<7169, 256, 0, stream>>>(wq, wk, wv, wo, w1, w2, bq, bk, bv, bo,
                                            wqkvT, woT, w1F8, w2F8, bqkv, cboW,
                                            x, xn, ln1a, ln1b);
  // fused q|k|v GEMM (bf16): Q row-major -> qRM, K and V transposed -> kvT.
  mfma_gemm<128, 128, true, false, false, 1024, false, 12, 8>
      <<<dim3(24, 32), 256, 0, stream>>>(
      xn, wqkvT, bqkv, nullptr, qRM, kvT, 1024, 1024, 1024, 1024);
  // fused masked moment + W' + cbo (one launch, 64 blocks x 512 thr)
  moment_kernel<<<64, 512, 0, stream>>>(kvT, mask, woT, Wbt, cboW);
  // batched attention+wo GEMM: x1 = x + Q*W'_b + cbo_b  (bf16)
  mfma_gemm<128, 64, true, false, true, 0, true, 8, 8>
      <<<dim3(16, 32), 256, 0, stream>>>(
      qRM, Wbt, cboW, x, x1, nullptr, 1024, 1024, 1024, 1024);
  // LN2: x1 -> xn2 fp8
  ln2_kernel<<<4096, 256, 0, stream>>>(x1, ln2a, ln2b, xn2f8);
  // FFN1 fp8: 1024 blocks, BK=128, relu -> fp8 hb
  mfma_gemm_fp8<true, 128, 16, 8><<<dim3(32, 32), 256, 0, stream>>>(
      xn2f8, w1F8, b1, nullptr, hbF8, 4096, 1024, 1024, 1024);
  // FFN2 fp8 z=1, TM128xTN64 (512 blocks), K=4096; epilogue: +b2 +x1 -> out
  mfma_gemm_fp8<false, 64, 8, 8><<<dim3(16, 32), 256, 0, stream>>>(
      hbF8, w2F8, b2, x1, out, 1024, 4096, 4096, 4096);
}